// Round 11
// baseline (251.598 us; speedup 1.0000x reference)
//
#include <hip/hip_runtime.h>
#include <stdint.h>

#define DEV __device__ __forceinline__

typedef __bf16 bf16x8 __attribute__((ext_vector_type(8)));
typedef float f32x4 __attribute__((ext_vector_type(4)));

DEV ushort f2bf(float f) {
    union { float f; uint32_t u; } v; v.f = f;
    uint32_t r = v.u + 0x7FFFu + ((v.u >> 16) & 1u);
    return (ushort)(r >> 16);
}

DEV ushort bfc(float f) {
    union { __bf16 h; ushort u; } v;
    v.h = (__bf16)f;
    return v.u;
}

DEV void gld16(const void* g, void* lds) {
    __builtin_amdgcn_global_load_lds(
        (const __attribute__((address_space(1))) void*)g,
        (__attribute__((address_space(3))) void*)lds, 16, 0, 0);
}

DEV bf16x8 ld_frag(const void* p) { return *(const bf16x8*)p; }

// ---------------- fp32 -> bf16 converts ----------------
__global__ void cvt_kernel(const float* __restrict__ in, ushort* __restrict__ out, int n4) {
    int i = blockIdx.x * blockDim.x + threadIdx.x;
    if (i >= n4) return;
    float4 v = ((const float4*)in)[i];
    ushort4 o;
    o.x = f2bf(v.x); o.y = f2bf(v.y); o.z = f2bf(v.z); o.w = f2bf(v.w);
    ((ushort4*)out)[i] = o;
}

// 4 weight matrices; Wq (y==0) pre-scaled by log2(e)/8 so QK^T lands directly
// in exp2 domain (removes one VALU mul per P element in attention).
__global__ void cvt4_kernel(const float* __restrict__ w0, const float* __restrict__ w1,
                            const float* __restrict__ w2, const float* __restrict__ w3,
                            ushort* __restrict__ out, int n4) {
    int i = blockIdx.x * blockDim.x + threadIdx.x;
    if (i >= n4) return;
    const float* src = (blockIdx.y == 0) ? w0 : (blockIdx.y == 1) ? w1
                     : (blockIdx.y == 2) ? w2 : w3;
    const float scl = (blockIdx.y == 0) ? 0.18033688011116013f : 1.0f;
    float4 v = ((const float4*)src)[i];
    ushort4 o;
    o.x = f2bf(v.x * scl); o.y = f2bf(v.y * scl);
    o.z = f2bf(v.z * scl); o.w = f2bf(v.w * scl);
    ((ushort4*)(out + (size_t)blockIdx.y * n4 * 4))[i] = o;
}

// ============ 256x256 deep-phase bf16 GEMM: C = A[M,K] * B[N,K]^T ============
// 512 threads = 8 waves (2M x 4N), per-wave 128x64 output, BK=64.
// BURST staging: all 4 half-tiles for kt+1 issued at the TOP of tile kt
// (max lead ~4 phases ≈ 400 cyc >= L2 latency) -> the single end-of-tile
// vmcnt(0) drain finds loads already landed.
DEV void stage_half(const ushort* Mp, int grow0, int k0, char* ldsbase, int t, int K) {
#pragma unroll
    for (int i = 0; i < 2; ++i) {
        int o = (i * 512 + t) * 16;
        int row = o >> 7;
        int cs = ((o >> 4) & 7) ^ (row & 7);
        gld16((const char*)Mp + ((size_t)(grow0 + row) * K + k0) * 2 + cs * 16, ldsbase + o);
    }
}

DEV void gphase(const char* Ab, const char* Bb, f32x4 acc[8][4],
                int wr, int wc, int rA, int cc, int mh, int nh) {
    bf16x8 af[4][2], bg[2][2];
#pragma unroll
    for (int i2 = 0; i2 < 4; ++i2)
#pragma unroll
        for (int kc = 0; kc < 2; ++kc) {
            int ra = wr * 128 + mh * 64 + i2 * 16 + rA;
            af[i2][kc] = ld_frag(Ab + ra * 128 + (((kc * 4 + cc) ^ (ra & 7)) * 16));
        }
#pragma unroll
    for (int j2 = 0; j2 < 2; ++j2)
#pragma unroll
        for (int kc = 0; kc < 2; ++kc) {
            int rb = wc * 64 + nh * 32 + j2 * 16 + rA;
            bg[j2][kc] = ld_frag(Bb + rb * 128 + (((kc * 4 + cc) ^ (rb & 7)) * 16));
        }
    __builtin_amdgcn_s_setprio(1);
#pragma unroll
    for (int kc = 0; kc < 2; ++kc)
#pragma unroll
        for (int i2 = 0; i2 < 4; ++i2)
#pragma unroll
            for (int j2 = 0; j2 < 2; ++j2)
                acc[mh * 4 + i2][nh * 2 + j2] = __builtin_amdgcn_mfma_f32_16x16x32_bf16(
                    af[i2][kc], bg[j2][kc], acc[mh * 4 + i2][nh * 2 + j2], 0, 0, 0);
    __builtin_amdgcn_s_setprio(0);
}

template<int F32OUT>
__global__ __launch_bounds__(512, 2) void gemm256(const ushort* __restrict__ A,
                                                  const ushort* __restrict__ B,
                                                  void* __restrict__ C,
                                                  int M, int N, int K) {
    __shared__ __align__(16) ushort S[2][2][16384];   // [buf][A/B][256*64]
    const int G = gridDim.x;
    const int bid = blockIdx.x;
    const int swz = (bid & 7) * (G >> 3) + (bid >> 3);   // G % 8 == 0
    const int nbn = N >> 8;
    const int bm = swz / nbn, bn = swz % nbn;
    const int t = threadIdx.x, l = t & 63, w = t >> 6;
    const int wr = w >> 2, wc = w & 3;
    const int rA = l & 15, cc = l >> 4;
    f32x4 acc[8][4] = {};
    const int NT = K >> 6;

    stage_half(A, bm * 256,       0, (char*)S[0][0],         t, K);
    stage_half(A, bm * 256 + 128, 0, (char*)S[0][0] + 16384, t, K);
    stage_half(B, bn * 256,       0, (char*)S[0][1],         t, K);
    stage_half(B, bn * 256 + 128, 0, (char*)S[0][1] + 16384, t, K);
    asm volatile("s_waitcnt vmcnt(0)" ::: "memory");
    __builtin_amdgcn_s_barrier();

    for (int kt = 0; kt < NT; ++kt) {
        const int buf = kt & 1;
        const char* Ab = (const char*)S[buf][0];
        const char* Bb = (const char*)S[buf][1];
        char* An = (char*)S[buf ^ 1][0];
        char* Bn = (char*)S[buf ^ 1][1];
        const int k1 = (kt + 1) << 6;
        if (kt + 1 < NT) {                       // burst: all staging up front
            stage_half(A, bm * 256,       k1, An,         t, K);
            stage_half(A, bm * 256 + 128, k1, An + 16384, t, K);
            stage_half(B, bn * 256,       k1, Bn,         t, K);
            stage_half(B, bn * 256 + 128, k1, Bn + 16384, t, K);
        }
        gphase(Ab, Bb, acc, wr, wc, rA, cc, 0, 0);
        gphase(Ab, Bb, acc, wr, wc, rA, cc, 0, 1);
        gphase(Ab, Bb, acc, wr, wc, rA, cc, 1, 0);
        gphase(Ab, Bb, acc, wr, wc, rA, cc, 1, 1);
        asm volatile("s_waitcnt vmcnt(0)" ::: "memory");
        __builtin_amdgcn_s_barrier();
    }

#pragma unroll
    for (int i = 0; i < 8; ++i)
#pragma unroll
        for (int j = 0; j < 4; ++j)
#pragma unroll
            for (int r = 0; r < 4; ++r) {
                int row = bm * 256 + wr * 128 + i * 16 + cc * 4 + r;
                int col = bn * 256 + wc * 64 + j * 16 + rA;
                if (F32OUT) ((float*)C)[(size_t)row * N + col] = acc[i][j][r];
                else        ((ushort*)C)[(size_t)row * N + col] = f2bf(acc[i][j][r]);
            }
}

// ------- bf16 GEMM 128x128, double-buffered (out-proj) -------
// Same stage-next -> compute-cur -> vmcnt(0)+barrier pattern as attn loop.
template<int F32OUT>
__global__ __launch_bounds__(256) void gemm_bt(const ushort* __restrict__ A,
                                               const ushort* __restrict__ B,
                                               void* __restrict__ C,
                                               int M, int N, int K) {
    __shared__ __align__(16) ushort As[2][128 * 64];
    __shared__ __align__(16) ushort Bs[2][128 * 64];
    const int G = gridDim.x;
    const int bid = blockIdx.x;
    const int swz = (bid & 7) * (G >> 3) + (bid >> 3);   // G % 8 == 0
    const int bm = swz & 63, bn = swz >> 6;
    const int t = threadIdx.x, l = t & 63, w = t >> 6;
    const int wm = w >> 1, wn = w & 1;
    const int rA = l & 15, cc = l >> 4;
    f32x4 acc[4][4] = {};
    const int NT = K >> 6;

#define STAGE_AB(k0, sb)                                                              \
    {                                                                                  \
        _Pragma("unroll")                                                              \
        for (int i = 0; i < 4; ++i) {                                                  \
            int o = (w * 4 + i) * 1024 + l * 16;                                       \
            int row = o >> 7;                                                          \
            int cs = ((o >> 4) & 7) ^ (row & 7);                                       \
            gld16((const char*)A + (((size_t)(bm * 128 + row)) * K + (k0)) * 2 + cs * 16, \
                  (char*)As[sb] + o);                                                  \
            gld16((const char*)B + (((size_t)(bn * 128 + row)) * K + (k0)) * 2 + cs * 16, \
                  (char*)Bs[sb] + o);                                                  \
        }                                                                              \
    }

    STAGE_AB(0, 0);
    asm volatile("s_waitcnt vmcnt(0)" ::: "memory");
    __builtin_amdgcn_s_barrier();

    for (int kt = 0; kt < NT; ++kt) {
        const int sb = kt & 1;
        if (kt + 1 < NT) STAGE_AB((kt + 1) << 6, sb ^ 1);
        const char* Ab = (const char*)As[sb];
        const char* Bb = (const char*)Bs[sb];
        bf16x8 af[4][2], bfr[4][2];
#pragma unroll
        for (int i = 0; i < 4; ++i) {
#pragma unroll
            for (int kc = 0; kc < 2; ++kc) {
                int ra = wm * 64 + i * 16 + rA;
                af[i][kc] = ld_frag(Ab + ra * 128 + (((kc * 4 + cc) ^ (ra & 7)) * 16));
                int rb = wn * 64 + i * 16 + rA;
                bfr[i][kc] = ld_frag(Bb + rb * 128 + (((kc * 4 + cc) ^ (rb & 7)) * 16));
            }
        }
        __builtin_amdgcn_s_setprio(1);
#pragma unroll
        for (int kc = 0; kc < 2; ++kc)
#pragma unroll
            for (int i = 0; i < 4; ++i)
#pragma unroll
                for (int j = 0; j < 4; ++j)
                    acc[i][j] = __builtin_amdgcn_mfma_f32_16x16x32_bf16(
                        af[i][kc], bfr[j][kc], acc[i][j], 0, 0, 0);
        __builtin_amdgcn_s_setprio(0);
        asm volatile("s_waitcnt vmcnt(0)" ::: "memory");
        __builtin_amdgcn_s_barrier();
    }
#undef STAGE_AB
#pragma unroll
    for (int i = 0; i < 4; ++i)
#pragma unroll
        for (int j = 0; j < 4; ++j)
#pragma unroll
            for (int r = 0; r < 4; ++r) {
                int row = bm * 128 + wm * 64 + i * 16 + cc * 4 + r;
                int col = bn * 128 + wn * 64 + j * 16 + rA;
                if (F32OUT) ((float*)C)[(size_t)row * N + col] = acc[i][j][r];
                else        ((ushort*)C)[(size_t)row * N + col] = f2bf(acc[i][j][r]);
            }
}

// ---------------- V transpose: qkv V-part -> vt[bh][d][s] ----------------
__global__ __launch_bounds__(256) void vtrans_kernel(const ushort* __restrict__ qkv,
                                                     ushort* __restrict__ vt) {
    __shared__ ushort tile[64][68];
    const int st = blockIdx.x, bh = blockIdx.y;
    const int b = bh >> 4, h = bh & 15;
    const int t = threadIdx.x;
    const ushort* src = qkv + (size_t)(b * 2048 + st * 64) * 3072 + 2048 + h * 64;
#pragma unroll
    for (int i = 0; i < 2; ++i) {
        int idx = t + i * 256;
        int s = idx >> 3, d0 = (idx & 7) * 8;
        uint4 v = *(const uint4*)(src + (size_t)s * 3072 + d0);
        *(uint2*)&tile[s][d0]     = make_uint2(v.x, v.y);
        *(uint2*)&tile[s][d0 + 4] = make_uint2(v.z, v.w);
    }
    __syncthreads();
    ushort* dst = vt + (size_t)bh * 64 * 2048 + st * 64;
#pragma unroll
    for (int i = 0; i < 2; ++i) {
        int idx = t + i * 256;
        int d = idx >> 3, s0 = (idx & 7) * 8;
        ushort tmp[8];
#pragma unroll
        for (int j = 0; j < 8; ++j) tmp[j] = tile[s0 + j][d];
        *(uint4*)(dst + (size_t)d * 2048 + s0) = *(uint4*)tmp;
    }
}

// ---------------- causal flash attention ----------------
// Swapped-operand: S^T = mfma(K, Q_prescaled) lands directly in exp2 domain;
// fixed m=0; O^T = mfma(V^T, P^T); l accumulated via ones-MFMA (row-sum of
// the SAME bf16 P used for PV) -> no per-element adds, no epilogue shuffles.
DEV void stage_kv(const char* Kg0, const char* Vg0, int kv0,
                  char* KsB, char* VsB, int t) {
    int row = t >> 3;
    int cs = (t & 7) ^ (row & 7);
    gld16(Kg0 + (size_t)(kv0 + row) * 6144 + cs * 16, KsB + t * 16);
    gld16(Vg0 + (size_t)row * 4096 + (size_t)kv0 * 2 + cs * 16, VsB + t * 16);
}

DEV void attn_tile(const char* KsB, const char* VsB, char* PsW,
                   const bf16x8* qf, f32x4* oacc, f32x4& osum, const bf16x8 ones,
                   int rA, int cc, int qg, int kv0, bool diag) {
    f32x4 s[4] = {};
    __builtin_amdgcn_s_setprio(1);
#pragma unroll
    for (int kc = 0; kc < 2; ++kc)
#pragma unroll
        for (int c = 0; c < 4; ++c) {
            int rk = c * 16 + rA;
            int ck = (kc * 4 + cc) ^ (rk & 7);
            bf16x8 ak = ld_frag(KsB + rk * 128 + ck * 16);
            s[c] = __builtin_amdgcn_mfma_f32_16x16x32_bf16(ak, qf[kc], s[c], 0, 0, 0);
        }
    __builtin_amdgcn_s_setprio(0);
    const int swz = (rA & 7) << 4;
#pragma unroll
    for (int c = 0; c < 4; ++c) {
        float pv[4];
#pragma unroll
        for (int r = 0; r < 4; ++r) {
            float v = s[c][r];                       // already log2-domain
            if (diag && (kv0 + c * 16 + cc * 4 + r > qg)) v = -1e30f;
            pv[r] = __builtin_amdgcn_exp2f(v);
        }
        union { ushort us[4]; uint2 u2; } pk;
        pk.us[0] = bfc(pv[0]); pk.us[1] = bfc(pv[1]);
        pk.us[2] = bfc(pv[2]); pk.us[3] = bfc(pv[3]);
        *(uint2*)(PsW + rA * 128 + ((32 * c + 8 * cc) ^ swz)) = pk.u2;
    }
    bf16x8 ap[2];
    ap[0] = ld_frag(PsW + rA * 128 + ((16 * cc) ^ swz));
    ap[1] = ld_frag(PsW + rA * 128 + ((64 + 16 * cc) ^ swz));
    __builtin_amdgcn_s_setprio(1);
    osum = __builtin_amdgcn_mfma_f32_16x16x32_bf16(ones, ap[0], osum, 0, 0, 0);
    osum = __builtin_amdgcn_mfma_f32_16x16x32_bf16(ones, ap[1], osum, 0, 0, 0);
#pragma unroll
    for (int kc = 0; kc < 2; ++kc)
#pragma unroll
        for (int g = 0; g < 4; ++g) {
            int rv = g * 16 + rA;
            int cv = (kc * 4 + cc) ^ (rv & 7);
            bf16x8 av = ld_frag(VsB + rv * 128 + cv * 16);
            oacc[g] = __builtin_amdgcn_mfma_f32_16x16x32_bf16(av, ap[kc], oacc[g], 0, 0, 0);
        }
    __builtin_amdgcn_s_setprio(0);
}

// 1D grid of 512 blocks; XCD co-location: all 8 q-pair blocks of one (b,h)
// on one XCD so its K/V stream stays in that XCD's L2 (R4: FETCH 170->31MB).
__global__ __launch_bounds__(512, 4) void attn_kernel(const ushort* __restrict__ qkv,
                                                      const ushort* __restrict__ vt,
                                                      ushort* __restrict__ o_out) {
    const int i = blockIdx.x;
    const int xcd = i & 7, slot = i >> 3;
    const int p = slot >> 3;
    const int bh = ((slot & 7) << 3) | xcd;
    const int ftq = 15 - p;
    const int b = bh >> 4, h = bh & 15;
    const int t = threadIdx.x, l = t & 63, w = t >> 6;
    const int rA = l & 15, cc = l >> 4;
    const int wq16 = w * 16;

    __shared__ __align__(16) ushort Ks[2][64 * 64];
    __shared__ __align__(16) ushort Vs[2][64 * 64];
    __shared__ __align__(16) ushort Ps[8][16 * 64];

    const size_t xbase = (size_t)(b * 2048) * 3072 + (size_t)h * 64;
    const char* Kg0 = (const char*)(qkv + xbase + 1024);
    const char* Vg0 = (const char*)(vt + (size_t)bh * 64 * 2048);

    const int qgN = p * 128 + wq16 + rA;
    const int qgF = ftq * 128 + wq16 + rA;

    bf16x8 qfN[2], qfF[2];
    {
        const ushort* qpN = qkv + xbase + (size_t)qgN * 3072;
        const ushort* qpF = qkv + xbase + (size_t)qgF * 3072;
        qfN[0] = *(const bf16x8*)(qpN + cc * 8);
        qfN[1] = *(const bf16x8*)(qpN + 32 + cc * 8);
        qfF[0] = *(const bf16x8*)(qpF + cc * 8);
        qfF[1] = *(const bf16x8*)(qpF + 32 + cc * 8);
    }
    bf16x8 ones;
#pragma unroll
    for (int z = 0; z < 8; ++z) ones[z] = (__bf16)1.0f;

    f32x4 oN[4] = {}, oF[4] = {};
    f32x4 osN = {}, osF = {};

    const int nkv = 32 - 2 * p;
    stage_kv(Kg0, Vg0, 0, (char*)Ks[0], (char*)Vs[0], t);
    asm volatile("s_waitcnt vmcnt(0)" ::: "memory");
    __builtin_amdgcn_s_barrier();

    for (int kt = 0; kt < nkv; ++kt) {
        const int cur = kt & 1;
        if (kt + 1 < nkv)
            stage_kv(Kg0, Vg0, (kt + 1) * 64, (char*)Ks[cur ^ 1], (char*)Vs[cur ^ 1], t);
        const char* KsB = (const char*)Ks[cur];
        const char* VsB = (const char*)Vs[cur];
        attn_tile(KsB, VsB, (char*)Ps[w], qfF, oF, osF, ones, rA, cc, qgF, kt * 64, kt >= nkv - 2);
        if (kt <= 2 * p + 1)
            attn_tile(KsB, VsB, (char*)Ps[w], qfN, oN, osN, ones, rA, cc, qgN, kt * 64, kt >= 2 * p);
        asm volatile("s_waitcnt vmcnt(0)" ::: "memory");
        __builtin_amdgcn_s_barrier();
    }

    const float rf = 1.0f / osF[0], rn = 1.0f / osN[0];
    const size_t obF = (size_t)(b * 2048 + qgF) * 1024 + h * 64;
    const size_t obN = (size_t)(b * 2048 + qgN) * 1024 + h * 64;
#pragma unroll
    for (int g = 0; g < 4; ++g) {
        union { ushort us[4]; uint2 u2; } pf, pn;
#pragma unroll
        for (int r = 0; r < 4; ++r) {
            pf.us[r] = bfc(oF[g][r] * rf);
            pn.us[r] = bfc(oN[g][r] * rn);
        }
        *(uint2*)(o_out + obF + 16 * g + 4 * cc) = pf.u2;
        *(uint2*)(o_out + obN + 16 * g + 4 * cc) = pn.u2;
    }
}

extern "C" void kernel_launch(void* const* d_in, const int* in_sizes, int n_in,
                              void* d_out, int out_size, void* d_ws, size_t ws_size,
                              hipStream_t stream) {
    const float* x  = (const float*)d_in[0];
    const float* Wq = (const float*)d_in[1];
    const float* Wk = (const float*)d_in[2];
    const float* Wv = (const float*)d_in[3];
    const float* Wo = (const float*)d_in[4];
    float* out = (float*)d_out;

    const int M = 8192, D = 1024;          // M = B*S
    char* ws = (char*)d_ws;
    ushort* xo_bf = (ushort*)ws;                                   // x bf16, later attn-out
    ushort* wqkv  = (ushort*)(ws + (size_t)M * D * 2);             // Wq,Wk,Wv,Wo contiguous
    ushort* wo_bf = (ushort*)(ws + (size_t)M * D * 2 + (size_t)3 * D * D * 2);
    ushort* qkv   = (ushort*)(ws + (size_t)M * D * 2 + (size_t)4 * D * D * 2);
    ushort* vt    = (ushort*)d_out;        // V^T scratch inside d_out; overwritten by final GEMM

    cvt_kernel<<<dim3(M * D / 4 / 256), 256, 0, stream>>>(x, xo_bf, M * D / 4);
    cvt4_kernel<<<dim3(D * D / 4 / 256, 4), 256, 0, stream>>>(Wq, Wk, Wv, Wo, wqkv, D * D / 4);

    // QKV = x @ Wqkv^T  [8192,3072] bf16 — 256² burst-staged, 384 wg, XCD-swizzled
    gemm256<0><<<dim3((M / 256) * (3072 / 256)), 512, 0, stream>>>(xo_bf, wqkv, qkv, M, 3072, D);

    // V^T into d_out scratch
    vtrans_kernel<<<dim3(32, 64), 256, 0, stream>>>(qkv, vt);

    // causal flash attention (128-row paired q-tiles, XCD-colocated, dbuf KV)
    attn_kernel<<<dim3(512), 512, 0, stream>>>(qkv, vt, xo_bf);

    // out = attn_out @ Wo^T   fp32 (512 wg, dbuf, XCD-swizzled; overwrites vt)
    gemm_bt<1><<<dim3((M / 128) * (D / 128)), 256, 0, stream>>>(xo_bf, wo_bf, out, M, D, D);
}